// Round 3
// baseline (420.618 us; speedup 1.0000x reference)
//
#include <hip/hip_runtime.h>

// Problem constants (from reference) — all fp32 I/O, int32 indices.
#define BB 32
#define NN 8192
#define DIM 256
#define MM 1228
#define X_ELEMS ((size_t)BB * NN * DIM)   // 67,108,864 fp32 in masked_x
#define ROWS (BB * NN)                    // 262,144 (b, n) rows, 1 KB each
#define F4_PER_ROW (DIM / 4)              // 64 float4 per row
#define TOTAL_F4 (X_ELEMS / 4)            // 16,777,216 float4
#define NMASK (BB * MM)                   // 39,296 masked rows total

// --- fused-flag path -------------------------------------------------------

// Zero the per-row flag array (256 KB in d_ws). 65,536 threads x 4 B.
__global__ void aug_zero_flags(unsigned* __restrict__ flags32) {
    int t = blockIdx.x * blockDim.x + threadIdx.x;   // exact grid: ROWS/4
    flags32[t] = 0u;
}

// Mark masked rows; also emit output 1 (indices as fp32).
__global__ void aug_flags(const int* __restrict__ idx,
                          unsigned char* __restrict__ flags,
                          float* __restrict__ out_idx) {
    int t = blockIdx.x * blockDim.x + threadIdx.x;
    if (t >= NMASK) return;
    int b = t / MM;                 // const divisor -> magic multiply
    int n = idx[t];                 // [0, NN)
    flags[b * NN + n] = 1;
    out_idx[t] = (float)n;
}

// One wave per row: copy x row or broadcast emb row. Branch is wave-uniform.
__global__ void aug_main(const float4* __restrict__ x,
                         const float4* __restrict__ emb,     // 64 float4 = 1 KB
                         const unsigned char* __restrict__ flags,
                         float4* __restrict__ out) {
    unsigned t = blockIdx.x * blockDim.x + threadIdx.x;      // exact grid: TOTAL_F4
    unsigned row = t >> 6;
    unsigned lane = t & 63;
    if (flags[row]) {               // wave-uniform; emb is L1-resident
        out[t] = emb[lane];
        return;                     // skip x fetch for masked rows
    }
    out[t] = x[t];
}

// --- fallback path (no workspace needed) -----------------------------------

__global__ void aug_copy(const float4* __restrict__ x, float4* __restrict__ out) {
    unsigned t = blockIdx.x * blockDim.x + threadIdx.x;      // exact grid
    out[t] = x[t];
}

__global__ void aug_scatter(const int* __restrict__ idx,
                            const float4* __restrict__ emb,
                            float4* __restrict__ out,
                            float* __restrict__ out_idx) {
    int t = blockIdx.x * blockDim.x + threadIdx.x;           // exact grid: NMASK*64
    int row = t >> 6;
    int lane = t & 63;
    int b = row / MM;
    int n = idx[row];
    size_t base = ((size_t)b * NN + (size_t)n) * F4_PER_ROW;
    out[base + lane] = emb[lane];
    if (lane == 0) out_idx[row] = (float)n;
}

extern "C" void kernel_launch(void* const* d_in, const int* in_sizes, int n_in,
                              void* d_out, int out_size, void* d_ws, size_t ws_size,
                              hipStream_t stream) {
    const float4* x   = (const float4*)d_in[0];   // fp32 [B, N, DIM]
    const int*    idx = (const int*)d_in[1];      // int32 [B, M]
    const float4* emb = (const float4*)d_in[2];   // fp32 [1, DIM]
    float* out = (float*)d_out;                   // fp32: masked_x ++ indices

    if (ws_size >= (size_t)ROWS && d_ws != nullptr) {
        unsigned char* flags = (unsigned char*)d_ws;
        aug_zero_flags<<<ROWS / 4 / 256, 256, 0, stream>>>((unsigned*)flags);
        aug_flags<<<(NMASK + 255) / 256, 256, 0, stream>>>(idx, flags, out + X_ELEMS);
        aug_main<<<TOTAL_F4 / 256, 256, 0, stream>>>(x, emb, flags, (float4*)d_out);
    } else {
        aug_copy<<<TOTAL_F4 / 256, 256, 0, stream>>>(x, (float4*)d_out);
        aug_scatter<<<(NMASK * 64) / 256, 256, 0, stream>>>(
            idx, emb, (float4*)d_out, out + X_ELEMS);
    }
}